// Round 1
// baseline (63.693 us; speedup 1.0000x reference)
//
#include <hip/hip_runtime.h>
#include <math.h>

// ---------------------------------------------------------------------------
// ZBL repulsion:
//   per pair p: dist = |disp[p] + (1-bm[p])|
//               switch_off = smooth_switch(dist, 0, 10)
//               za_sum = Z_i^0.23-ish terms -> a_ij -> arg
//               phi = sum_k c_k exp(-e_k*arg)   (max-log trick like ref)
//               rep = clamp(0.5*Zi*Zj/dist * phi * switch) * bm
//   Erep[i] = clip(segment_sum_i(rep) * atom_mask, 0, 1e6) * 0.01
// idx_i is SORTED -> wave-level segmented reduction, atomicAdd per run head.
// ---------------------------------------------------------------------------

__global__ void zbl_setup_tab(const float* __restrict__ an,
                              const float* __restrict__ a_exp_ptr,
                              float2* __restrict__ tab, int n) {
    int i = blockIdx.x * blockDim.x + threadIdx.x;
    if (i >= n) return;
    float ae = fabsf(a_exp_ptr[0]);
    float sa = fmaxf(an[i], 1e-6f);
    float z  = expf(logf(sa) * ae);
    if (!(z == z)) z = 1e-6f;       // nan -> 1e-6
    z = fminf(z, 1e6f);             // posinf clamp
    tab[i] = make_float2(z, sa);
}

template <bool USE_TAB>
__global__ __launch_bounds__(256) void zbl_pair_kernel(
    const float* __restrict__ disp,        // [P*3]
    const int*   __restrict__ idx_i,       // sorted
    const int*   __restrict__ idx_j,
    const float* __restrict__ batch_mask,  // [P]
    const float2* __restrict__ tab,        // {za, safe_Z} per atom (if USE_TAB)
    const float* __restrict__ an,          // atomic numbers (fallback path)
    const float* __restrict__ a_coef_ptr,  // 1
    const float* __restrict__ a_exp_ptr,   // 1 (fallback path)
    const float* __restrict__ phi_c,       // 4
    const float* __restrict__ phi_e,       // 4
    float* __restrict__ out_acc,           // [N] accumulator (pre-zeroed)
    int nP)
{
    __shared__ float sdisp[256 * 3];
    const int tid  = threadIdx.x;
    const int base = blockIdx.x * 256;

    // ---- stage 256 pairs' displacements (768 floats = 192 float4), coalesced
    {
        long gbase = (long)base * 3;
        long total = (long)nP * 3;
        if (tid < 192) {
            long g = gbase + (long)tid * 4;
            if (g + 3 < total) {
                float4 v = *reinterpret_cast<const float4*>(disp + g);
                reinterpret_cast<float4*>(sdisp)[tid] = v;
            } else {
                #pragma unroll
                for (int k = 0; k < 4; ++k)
                    sdisp[tid * 4 + k] = (g + k < total) ? disp[g + k] : 0.0f;
            }
        }
    }
    __syncthreads();

    const int p = base + tid;
    float rep = 0.0f;
    int   key = -1;

    if (p < nP) {
        float bm  = batch_mask[p];
        float add = 1.0f - bm;
        float dx = sdisp[tid * 3 + 0] + add;
        float dy = sdisp[tid * 3 + 1] + add;
        float dz = sdisp[tid * 3 + 2] + add;
        float dist = fmaxf(sqrtf(dx * dx + dy * dy + dz * dz), 1e-10f);

        // smooth_switch(dist, 0, 10)
        float t  = dist / 10.0f;
        float tc = fminf(fmaxf(t, 1e-9f), 1.0f - 1e-9f);
        float f1 = expf(-1.0f / tc);
        float f2 = expf(-1.0f / (1.0f - tc));
        float s  = f1 / (f1 + f2);
        float sw = (t <= 0.0f) ? 0.0f : ((t >= 1.0f) ? 1.0f : s);

        int ii = idx_i[p];
        int jj = idx_j[p];

        float za_i, za_j, sa_i, sa_j;
        if (USE_TAB) {
            float2 ti = tab[ii];
            float2 tj = tab[jj];
            za_i = ti.x; sa_i = ti.y;
            za_j = tj.x; sa_j = tj.y;
        } else {
            float ae = fabsf(a_exp_ptr[0]);
            sa_i = fmaxf(an[ii], 1e-6f);
            sa_j = fmaxf(an[jj], 1e-6f);
            za_i = fminf(expf(logf(sa_i) * ae), 1e6f);
            za_j = fminf(expf(logf(sa_j) * ae), 1e6f);
        }

        float za_sum = za_i + za_j;
        float aij = fabsf(a_coef_ptr[0]) / fmaxf(za_sum, 1e-6f);
        aij = fminf(aij, 1e6f);                       // nan_to_num posinf
        float arg = fmaxf(dist, 1e-10f) / fmaxf(aij, 1e-10f);
        arg = fminf(arg, 1e6f);

        float c0 = fabsf(phi_c[0]), c1 = fabsf(phi_c[1]);
        float c2 = fabsf(phi_c[2]), c3 = fabsf(phi_c[3]);
        float cinv = 1.0f / fmaxf(c0 + c1 + c2 + c3, 1e-10f);
        float e0 = fmaxf(fabsf(phi_e[0]), 1e-10f);
        float e1 = fmaxf(fabsf(phi_e[1]), 1e-10f);
        float e2 = fmaxf(fabsf(phi_e[2]), 1e-10f);
        float e3 = fmaxf(fabsf(phi_e[3]), 1e-10f);
        float l0 = -e0 * arg, l1 = -e1 * arg, l2 = -e2 * arg, l3 = -e3 * arg;
        float m  = fmaxf(fmaxf(l0, l1), fmaxf(l2, l3));
        float phi = (c0 * expf(l0 - m) + c1 * expf(l1 - m) +
                     c2 * expf(l2 - m) + c3 * expf(l3 - m)) * cinv * expf(m);
        phi = fmaxf(phi, 1e-30f);
        phi = fminf(phi, 1e6f);

        float cp   = fminf(sa_i * sa_j, 1e4f);
        float brep = fminf(0.5f * cp / dist, 1e6f);
        float r    = brep * phi * fmaxf(sw, 1e-30f);
        r = fminf(fmaxf(r, 0.0f), 1e6f);
        rep = r * bm;
        key = ii;
    }

    // ---- wave-level segmented suffix-sum on sorted keys
    const int lane = tid & 63;
    float v = rep;
    #pragma unroll
    for (int d = 1; d < 64; d <<= 1) {
        float nv = __shfl_down(v, d);
        int   nk = __shfl_down(key, d);
        if (lane + d < 64 && nk == key) v += nv;
    }
    int pk = __shfl_up(key, 1);
    bool head = (lane == 0) || (pk != key);
    if (head && key >= 0) {
        atomicAdd(&out_acc[key], v);
    }
}

__global__ void zbl_epilogue(float* __restrict__ out,
                             const float* __restrict__ atom_mask, int n) {
    int i = blockIdx.x * blockDim.x + threadIdx.x;
    if (i >= n) return;
    float v = out[i] * atom_mask[i];
    v = fminf(fmaxf(v, 0.0f), 1e6f);
    if (!(v == v)) v = 0.0f;
    out[i] = v * 0.01f;
}

extern "C" void kernel_launch(void* const* d_in, const int* in_sizes, int n_in,
                              void* d_out, int out_size, void* d_ws, size_t ws_size,
                              hipStream_t stream) {
    const float* an         = (const float*)d_in[0];
    const float* disp       = (const float*)d_in[1];
    const int*   idx_i      = (const int*)d_in[2];
    const int*   idx_j      = (const int*)d_in[3];
    const float* atom_mask  = (const float*)d_in[4];
    const float* batch_mask = (const float*)d_in[5];
    // d_in[6] batch_segments, d_in[7] batch_size: unused by the reference math
    const float* a_coef     = (const float*)d_in[8];
    const float* a_exp      = (const float*)d_in[9];
    const float* phi_c      = (const float*)d_in[10];
    const float* phi_e      = (const float*)d_in[11];

    const int nA = in_sizes[0];
    const int nP = in_sizes[2];
    float* out = (float*)d_out;

    // zero the accumulator (d_out) every call — deterministic
    hipMemsetAsync(d_out, 0, (size_t)out_size * sizeof(float), stream);

    const bool use_tab = (ws_size >= (size_t)nA * sizeof(float2));
    float2* tab = (float2*)d_ws;

    if (use_tab) {
        zbl_setup_tab<<<(nA + 255) / 256, 256, 0, stream>>>(an, a_exp, tab, nA);
        zbl_pair_kernel<true><<<(nP + 255) / 256, 256, 0, stream>>>(
            disp, idx_i, idx_j, batch_mask, tab, an, a_coef, a_exp, phi_c, phi_e, out, nP);
    } else {
        zbl_pair_kernel<false><<<(nP + 255) / 256, 256, 0, stream>>>(
            disp, idx_i, idx_j, batch_mask, (const float2*)nullptr, an, a_coef, a_exp,
            phi_c, phi_e, out, nP);
    }
    zbl_epilogue<<<(nA + 255) / 256, 256, 0, stream>>>(out, atom_mask, nA);
}

// Round 2
// 55.041 us; speedup vs baseline: 1.1572x; 1.1572x over previous
//
#include <hip/hip_runtime.h>
#include <math.h>

// ---------------------------------------------------------------------------
// ZBL repulsion, VALU-optimized round:
//  - native v_exp_f32 / v_rcp_f32 / v_sqrt_f32 via __builtin_amdgcn_*
//  - max-log trick folded away (e_k>0, arg>=0 -> rescale is algebraic no-op)
//  - smooth_switch as single-exp sigmoid: 1/(1+exp(1/tc - 1/(1-tc)))
//  - arg = dist * za_sum * rcp(|a_coef|) (division folded)
// idx_i SORTED -> wave-level segmented reduction, atomicAdd per run head.
// ---------------------------------------------------------------------------

#define LOG2E 1.4426950408889634f

static __device__ __forceinline__ float rcpf_(float x)  { return __builtin_amdgcn_rcpf(x); }
static __device__ __forceinline__ float exp2f_(float x) { return __builtin_amdgcn_exp2f(x); }
static __device__ __forceinline__ float sqrtf_(float x) { return __builtin_amdgcn_sqrtf(x); }
// exp(x) = 2^(x*log2e)
static __device__ __forceinline__ float expn_(float x)  { return exp2f_(x * LOG2E); }

__global__ void zbl_setup_tab(const float* __restrict__ an,
                              const float* __restrict__ a_exp_ptr,
                              float2* __restrict__ tab, int n) {
    int i = blockIdx.x * blockDim.x + threadIdx.x;
    if (i >= n) return;
    float ae = fabsf(a_exp_ptr[0]);
    float sa = fmaxf(an[i], 1e-6f);
    float z  = expf(logf(sa) * ae);   // one-time, libm precision
    if (!(z == z)) z = 1e-6f;
    z = fminf(z, 1e6f);
    tab[i] = make_float2(z, sa);
}

__global__ __launch_bounds__(256) void zbl_pair_kernel(
    const float* __restrict__ disp,        // [P*3]
    const int*   __restrict__ idx_i,       // sorted
    const int*   __restrict__ idx_j,
    const float* __restrict__ batch_mask,  // [P]
    const float2* __restrict__ tab,        // {za, safe_Z} per atom
    const float* __restrict__ a_coef_ptr,  // 1
    const float* __restrict__ phi_c,       // 4
    const float* __restrict__ phi_e,       // 4
    float* __restrict__ out_acc,           // [N] accumulator (pre-zeroed)
    int nP)
{
    __shared__ float sdisp[256 * 3];
    const int tid  = threadIdx.x;
    const int base = blockIdx.x * 256;

    // ---- stage 256 pairs' displacements (768 floats = 192 float4), coalesced
    {
        long gbase = (long)base * 3;
        long total = (long)nP * 3;
        if (tid < 192) {
            long g = gbase + (long)tid * 4;
            if (g + 3 < total) {
                float4 v = *reinterpret_cast<const float4*>(disp + g);
                reinterpret_cast<float4*>(sdisp)[tid] = v;
            } else {
                #pragma unroll
                for (int k = 0; k < 4; ++k)
                    sdisp[tid * 4 + k] = (g + k < total) ? disp[g + k] : 0.0f;
            }
        }
    }
    __syncthreads();

    const int p = base + tid;
    float rep = 0.0f;
    int   key = -1;

    if (p < nP) {
        float bm  = batch_mask[p];
        float add = 1.0f - bm;
        float dx = sdisp[tid * 3 + 0] + add;
        float dy = sdisp[tid * 3 + 1] + add;
        float dz = sdisp[tid * 3 + 2] + add;
        float dist = fmaxf(sqrtf_(dx * dx + dy * dy + dz * dz), 1e-10f);

        // smooth_switch(dist, 0, 10) as sigmoid: 1/(1+exp(1/tc - 1/(1-tc)))
        float t  = dist * 0.1f;
        float tc = fminf(fmaxf(t, 1e-9f), 1.0f - 1e-9f);
        float u  = rcpf_(tc) - rcpf_(1.0f - tc);
        float s  = rcpf_(1.0f + expn_(u));
        float sw = (t <= 0.0f) ? 0.0f : ((t >= 1.0f) ? 1.0f : s);

        int ii = idx_i[p];
        int jj = idx_j[p];
        float2 ti = tab[ii];
        float2 tj = tab[jj];

        // arg = dist / (|ac| / za_sum)  =  dist * za_sum / |ac|
        float za_sum = ti.x + tj.x;
        float arg = fminf(dist * za_sum * rcpf_(fmaxf(fabsf(a_coef_ptr[0]), 1e-10f)), 1e6f);

        // phi = cinv * sum_k c_k * exp(-e_k * arg)   (max-log trick is algebraic no-op)
        float c0 = fabsf(phi_c[0]), c1 = fabsf(phi_c[1]);
        float c2 = fabsf(phi_c[2]), c3 = fabsf(phi_c[3]);
        float cinv = rcpf_(fmaxf(c0 + c1 + c2 + c3, 1e-10f));
        float narg = -arg * LOG2E;  // exp(-e_k*arg) = 2^(-e_k*arg*log2e)
        float e0 = fmaxf(fabsf(phi_e[0]), 1e-10f);
        float e1 = fmaxf(fabsf(phi_e[1]), 1e-10f);
        float e2 = fmaxf(fabsf(phi_e[2]), 1e-10f);
        float e3 = fmaxf(fabsf(phi_e[3]), 1e-10f);
        float phi = (c0 * exp2f_(e0 * narg) + c1 * exp2f_(e1 * narg) +
                     c2 * exp2f_(e2 * narg) + c3 * exp2f_(e3 * narg)) * cinv;
        phi = fminf(fmaxf(phi, 1e-30f), 1e6f);

        float cp   = fminf(ti.y * tj.y, 1e4f);
        float brep = fminf(0.5f * cp * rcpf_(dist), 1e6f);
        float r    = brep * phi * fmaxf(sw, 1e-30f);
        r = fminf(fmaxf(r, 0.0f), 1e6f);
        if (!(r == r)) r = 0.0f;
        rep = r * bm;
        key = ii;
    }

    // ---- wave-level segmented suffix-sum on sorted keys
    const int lane = tid & 63;
    float v = rep;
    #pragma unroll
    for (int d = 1; d < 64; d <<= 1) {
        float nv = __shfl_down(v, d);
        int   nk = __shfl_down(key, d);
        if (lane + d < 64 && nk == key) v += nv;
    }
    int pk = __shfl_up(key, 1);
    bool head = (lane == 0) || (pk != key);
    if (head && key >= 0) {
        atomicAdd(&out_acc[key], v);
    }
}

__global__ void zbl_epilogue(float* __restrict__ out,
                             const float* __restrict__ atom_mask, int n) {
    int i = blockIdx.x * blockDim.x + threadIdx.x;
    if (i >= n) return;
    float v = out[i] * atom_mask[i];
    v = fminf(fmaxf(v, 0.0f), 1e6f);
    if (!(v == v)) v = 0.0f;
    out[i] = v * 0.01f;
}

extern "C" void kernel_launch(void* const* d_in, const int* in_sizes, int n_in,
                              void* d_out, int out_size, void* d_ws, size_t ws_size,
                              hipStream_t stream) {
    const float* an         = (const float*)d_in[0];
    const float* disp       = (const float*)d_in[1];
    const int*   idx_i      = (const int*)d_in[2];
    const int*   idx_j      = (const int*)d_in[3];
    const float* atom_mask  = (const float*)d_in[4];
    const float* batch_mask = (const float*)d_in[5];
    // d_in[6] batch_segments, d_in[7] batch_size: unused by the reference math
    const float* a_coef     = (const float*)d_in[8];
    const float* a_exp      = (const float*)d_in[9];
    const float* phi_c      = (const float*)d_in[10];
    const float* phi_e      = (const float*)d_in[11];

    const int nA = in_sizes[0];
    const int nP = in_sizes[2];
    float* out = (float*)d_out;

    hipMemsetAsync(d_out, 0, (size_t)out_size * sizeof(float), stream);

    float2* tab = (float2*)d_ws;   // ws_size is ample for 100k float2 (800 KB)

    zbl_setup_tab<<<(nA + 255) / 256, 256, 0, stream>>>(an, a_exp, tab, nA);
    zbl_pair_kernel<<<(nP + 255) / 256, 256, 0, stream>>>(
        disp, idx_i, idx_j, batch_mask, tab, a_coef, phi_c, phi_e, out, nP);
    zbl_epilogue<<<(nA + 255) / 256, 256, 0, stream>>>(out, atom_mask, nA);
}